// Round 8
// baseline (41.147 us; speedup 1.0000x reference)
//
#include <hip/hip_runtime.h>

// Problem constants (RES = 64)
#define RES       64
#define CM1       63
#define NCELL     250047      // 63^3
#define NTET      1500282     // NCELL*6
#define V_ELEMS   27005076    // NTET*18  (v_pos region, float32)
#define TRI_ELEMS 9001692     // NTET*6   (tri region, float32)
// valid region: NTET*2 floats after tri

#define TPB 256
#define NA  5861              // ceil(NTET/256)  : v_pos blocks (256 tets each)
#define NBC 1466              // ceil(NTET/1024) : tri blocks / valid blocks (1024 tets each)

__constant__ int c_TETS[6][4] = {
    {0,5,1,6},{0,1,2,6},{0,2,3,6},{0,3,7,6},{0,7,4,6},{0,4,5,6}
};
__constant__ int c_OFF[8][3] = {
    {0,0,0},{1,0,0},{1,1,0},{0,1,0},{0,0,1},{1,0,1},{1,1,1},{0,1,1}
};
// TET_TRIS[16][2][3] flattened; -1 = invalid
__constant__ int c_TRI[16][6] = {
    {-1,-1,-1,-1,-1,-1},{ 0, 3, 2,-1,-1,-1},{ 0, 1, 4,-1,-1,-1},{ 2, 3, 4, 2, 4, 1},
    { 1, 5, 2,-1,-1,-1},{ 0, 1, 5, 0, 5, 3},{ 0, 4, 5, 0, 5, 2},{ 3, 4, 5,-1,-1,-1},
    { 3, 5, 4,-1,-1,-1},{ 0, 2, 5, 0, 5, 4},{ 0, 3, 5, 0, 5, 1},{ 1, 2, 5,-1,-1,-1},
    { 1, 4, 3, 1, 3, 2},{ 0, 4, 1,-1,-1,-1},{ 0, 2, 3,-1,-1,-1},{-1,-1,-1,-1,-1,-1}
};

// decode tet id -> cell coords + tet index + level base offset
__device__ __forceinline__ void decode(int g, int& i, int& j, int& k, int& tet, int& base) {
    int cell = g / 6;
    tet  = g - cell * 6;
    i    = cell / (CM1 * CM1);
    int rem = cell - i * (CM1 * CM1);
    j    = rem / CM1;
    k    = rem - j * CM1;
    base = i * (RES * RES) + j * RES + k;
}

// case number for tet g (4 corner loads, f = -level)
__device__ __forceinline__ int tet_case(const float* __restrict__ level, int g) {
    int i, j, k, tet, base;
    decode(g, i, j, k, tet, base);
    int cs = 0;
    #pragma unroll
    for (int vi = 0; vi < 4; ++vi) {
        int c  = c_TETS[tet][vi];
        float f = -level[base + c_OFF[c][0] * (RES * RES) + c_OFF[c][1] * RES + c_OFF[c][2]];
        cs |= (f > 0.0f) ? (1 << vi) : 0;
    }
    return cs;
}

__global__ __launch_bounds__(TPB) void mc_kernel(const float* __restrict__ level,
                                                 float* __restrict__ out)
{
    __shared__ float s[6144];        // 24 KiB, shared by all block types

    int bid = blockIdx.x;
    int t   = threadIdx.x;
    int w   = t >> 6;                // wave id (0..3)
    int l   = t & 63;                // lane

    if (bid < NA) {
        // ---------- A: v_pos block — 256 tets, single 18 KB contiguous stream ----------
        int g0 = bid * TPB;
        int g  = g0 + t;
        int ntet = NTET - g0; if (ntet > TPB) ntet = TPB;
        int ntw  = ntet - w * 64; ntw = ntw < 0 ? 0 : (ntw > 64 ? 64 : ntw);   // even

        if (l < ntw) {
            int i, j, k, tet, base;
            decode(g, i, j, k, tet, base);
            float fv[4], px[4], py[4], pz[4];
            #pragma unroll
            for (int vi = 0; vi < 4; ++vi) {
                int c  = c_TETS[tet][vi];
                int ox = c_OFF[c][0], oy = c_OFF[c][1], oz = c_OFF[c][2];
                fv[vi] = -level[base + ox * (RES * RES) + oy * RES + oz];
                px[vi] = (float)(i + ox);
                py[vi] = (float)(j + oy);
                pz[vi] = (float)(k + oz);
            }
            const int EA[6] = {0, 1, 2, 0, 1, 2};
            const int EB[6] = {1, 2, 0, 3, 3, 3};
            const float inv63 = 1.0f / 63.0f;
            #pragma unroll
            for (int e = 0; e < 6; ++e) {
                int a = EA[e], b = EB[e];
                float fa = fv[a], fb = fv[b];
                float d  = fa - fb;
                float ds = (fabsf(d) < 1e-8f) ? 1e-8f : d;
                float tt = fa * __builtin_amdgcn_rcpf(ds);   // ~1 ulp, way under threshold
                tt = fminf(fmaxf(tt, 0.0f), 1.0f);
                float vx = px[a] + tt * (px[b] - px[a]);
                float vy = py[a] + tt * (py[b] - py[a]);
                float vz = pz[a] + tt * (pz[b] - pz[a]);
                s[t * 18 + e * 3 + 0] = vz * inv63;          // (z,y,x)/63
                s[t * 18 + e * 3 + 1] = vy * inv63;
                s[t * 18 + e * 3 + 2] = vx * inv63;
            }
        }
        __builtin_amdgcn_wave_barrier();   // wave-private slice; no block sync needed

        float4*       gv = (float4*)(out + (size_t)g0 * 18) + (size_t)w * 288;
        const float4* lv = (const float4*)s + w * 288;
        if (ntw == 64) {                   // 288 float4 = 4.5/lane
            #pragma unroll
            for (int n = 0; n < 4; ++n) gv[l + n * 64] = lv[l + n * 64];
            if (l < 32) gv[l + 256] = lv[l + 256];
        } else if (ntw > 0) {
            int n4 = (ntw * 18) >> 2;
            for (int idx = l; idx < n4; idx += 64) gv[idx] = lv[idx];
        }

    } else if (bid < NA + NBC) {
        // ---------- B: tri block — 1024 tets, single 24 KB contiguous stream ----------
        int bb    = bid - NA;
        int G0    = bb * 1024;
        int wbase = G0 + w * 256;
        int ntw   = NTET - wbase; ntw = ntw < 0 ? 0 : (ntw > 256 ? 256 : ntw);  // even

        #pragma unroll
        for (int tt = 0; tt < 4; ++tt) {
            int idx = tt * 64 + l;
            if (idx < ntw) {
                int g  = wbase + idx;
                int cs = tet_case(level, g);
                int base6 = g * 6;
                float* sp = &s[w * 1536 + idx * 6];
                #pragma unroll
                for (int n = 0; n < 6; ++n) {
                    int e = c_TRI[cs][n];
                    sp[n] = (float)(base6 + (e > 0 ? e : 0));   // < 2^24, exact
                }
            }
        }
        __builtin_amdgcn_wave_barrier();

        float4*       gt = (float4*)(out + V_ELEMS + (size_t)wbase * 6);
        const float4* lt = (const float4*)s + w * 384;
        if (ntw == 256) {                  // 384 float4 = exactly 6 full-wave passes
            #pragma unroll
            for (int p = 0; p < 6; ++p) gt[l + p * 64] = lt[l + p * 64];
        } else if (ntw > 0) {
            int n4 = (ntw * 6) >> 2;
            for (int idx = l; idx < n4; idx += 64) gt[idx] = lt[idx];
        }

    } else {
        // ---------- C: valid block — 1024 tets, single 8 KB contiguous stream ----------
        int cc    = bid - NA - NBC;
        int G0    = cc * 1024;
        int wbase = G0 + w * 256;
        int ntw   = NTET - wbase; ntw = ntw < 0 ? 0 : (ntw > 256 ? 256 : ntw);  // even

        #pragma unroll
        for (int tt = 0; tt < 4; ++tt) {
            int idx = tt * 64 + l;
            if (idx < ntw) {
                int g  = wbase + idx;
                int cs = tet_case(level, g);
                s[w * 512 + idx * 2 + 0] = (c_TRI[cs][0] >= 0) ? 1.0f : 0.0f;
                s[w * 512 + idx * 2 + 1] = (c_TRI[cs][3] >= 0) ? 1.0f : 0.0f;
            }
        }
        __builtin_amdgcn_wave_barrier();

        float4*       gl = (float4*)(out + V_ELEMS + TRI_ELEMS + (size_t)wbase * 2);
        const float4* ll = (const float4*)s + w * 128;
        if (ntw == 256) {                  // 128 float4 = exactly 2 full-wave passes
            gl[l]      = ll[l];
            gl[l + 64] = ll[l + 64];
        } else if (ntw > 0) {
            int n4 = (ntw * 2) >> 2;
            for (int idx = l; idx < n4; idx += 64) gl[idx] = ll[idx];
        }
    }
}

extern "C" void kernel_launch(void* const* d_in, const int* in_sizes, int n_in,
                              void* d_out, int out_size, void* d_ws, size_t ws_size,
                              hipStream_t stream) {
    const float* level = (const float*)d_in[0];
    float* out = (float*)d_out;
    mc_kernel<<<NA + 2 * NBC, TPB, 0, stream>>>(level, out);
}

// Round 9
// 30.841 us; speedup vs baseline: 1.3342x; 1.3342x over previous
//
#include <hip/hip_runtime.h>

// Problem constants (RES = 64)
#define RES       64
#define CM1       63
#define NCELL     250047      // 63^3
#define NTET      1500282     // NCELL*6
#define V_ELEMS   27005076    // NTET*18  (v_pos: 6 edges * 3 coords per tet, float32)
#define TRI_ELEMS 9001692     // NTET*6   (2 tris * 3 idx per tet, stored as float32)
// valid: NTET*2 float32 elements follow tri

#define TPB 256

__constant__ int c_TETS[6][4] = {
    {0,5,1,6},{0,1,2,6},{0,2,3,6},{0,3,7,6},{0,7,4,6},{0,4,5,6}
};
__constant__ int c_OFF[8][3] = {
    {0,0,0},{1,0,0},{1,1,0},{0,1,0},{0,0,1},{1,0,1},{1,1,1},{0,1,1}
};
// TET_TRIS[16][2][3] flattened; -1 = invalid
__constant__ int c_TRI[16][6] = {
    {-1,-1,-1,-1,-1,-1},  // 0
    { 0, 3, 2,-1,-1,-1},  // 1
    { 0, 1, 4,-1,-1,-1},  // 2
    { 2, 3, 4, 2, 4, 1},  // 3
    { 1, 5, 2,-1,-1,-1},  // 4
    { 0, 1, 5, 0, 5, 3},  // 5
    { 0, 4, 5, 0, 5, 2},  // 6
    { 3, 4, 5,-1,-1,-1},  // 7
    { 3, 5, 4,-1,-1,-1},  // 8
    { 0, 2, 5, 0, 5, 4},  // 9
    { 0, 3, 5, 0, 5, 1},  // 10
    { 1, 2, 5,-1,-1,-1},  // 11
    { 1, 4, 3, 1, 3, 2},  // 12
    { 0, 4, 1,-1,-1,-1},  // 13
    { 0, 2, 3,-1,-1,-1},  // 14
    {-1,-1,-1,-1,-1,-1}   // 15
};

__global__ __launch_bounds__(TPB) void mc_kernel(const float* __restrict__ level,
                                                 float* __restrict__ out)
{
    // LDS staging buffers laid out exactly like the per-block global regions.
    __shared__ float sv[TPB * 18];  // v_pos   18 KiB
    __shared__ float st[TPB * 6];   // tri      6 KiB
    __shared__ float sl[TPB * 2];   // valid    2 KiB

    int t  = threadIdx.x;
    int g0 = blockIdx.x * TPB;
    int g  = g0 + t;
    int ntet = NTET - g0; if (ntet > TPB) ntet = TPB;   // 256, or 122 in the tail block

    if (t < ntet) {
        int cell = g / 6;
        int tet  = g - cell * 6;
        int i    = cell / (CM1 * CM1);
        int rem  = cell - i * (CM1 * CM1);
        int j    = rem / CM1;
        int k    = rem - j * CM1;
        int base = i * (RES * RES) + j * RES + k;

        // Gather the 4 tet corners: f = -level, positions = (i,j,k)+offset
        float fv[4], px[4], py[4], pz[4];
        #pragma unroll
        for (int vi = 0; vi < 4; ++vi) {
            int c  = c_TETS[tet][vi];
            int ox = c_OFF[c][0], oy = c_OFF[c][1], oz = c_OFF[c][2];
            fv[vi] = -level[base + ox * (RES * RES) + oy * RES + oz];
            px[vi] = (float)(i + ox);
            py[vi] = (float)(j + oy);
            pz[vi] = (float)(k + oz);
        }

        int cs = (fv[0] > 0.0f ? 1 : 0) | (fv[1] > 0.0f ? 2 : 0)
               | (fv[2] > 0.0f ? 4 : 0) | (fv[3] > 0.0f ? 8 : 0);

        const int EA[6] = {0, 1, 2, 0, 1, 2};
        const int EB[6] = {1, 2, 0, 3, 3, 3};

        const float inv63 = 1.0f / 63.0f;
        #pragma unroll
        for (int e = 0; e < 6; ++e) {
            int a = EA[e], b = EB[e];
            float fa = fv[a], fb = fv[b];
            float d  = fa - fb;
            float ds = (fabsf(d) < 1e-8f) ? 1e-8f : d;
            float tt = fa / ds;                       // IEEE f32 divide, matches np exactly
            tt = fminf(fmaxf(tt, 0.0f), 1.0f);
            float vx = px[a] + tt * (px[b] - px[a]);
            float vy = py[a] + tt * (py[b] - py[a]);
            float vz = pz[a] + tt * (pz[b] - pz[a]);
            // reference reverses coord order: (z, y, x) / 63
            sv[t * 18 + e * 3 + 0] = vz * inv63;     // stride 18 -> 2-way bank alias (free)
            sv[t * 18 + e * 3 + 1] = vy * inv63;
            sv[t * 18 + e * 3 + 2] = vx * inv63;
        }

        int base6 = g * 6;
        #pragma unroll
        for (int tr = 0; tr < 2; ++tr) {
            int t0 = c_TRI[cs][tr * 3 + 0];
            int t1 = c_TRI[cs][tr * 3 + 1];
            int t2 = c_TRI[cs][tr * 3 + 2];
            sl[t * 2 + tr] = (t0 >= 0) ? 1.0f : 0.0f;
            int m0 = t0 > 0 ? t0 : 0;
            int m1 = t1 > 0 ? t1 : 0;
            int m2 = t2 > 0 ? t2 : 0;
            st[t * 6 + tr * 3 + 0] = (float)(base6 + m0);  // < 2^24, exact in f32
            st[t * 6 + tr * 3 + 1] = (float)(base6 + m1);
            st[t * 6 + tr * 3 + 2] = (float)(base6 + m2);
        }
    }

    __syncthreads();

    // Coalesced float4 copy-out. All counts divisible by 4 (ntet is even).
    {
        int n4 = (ntet * 18) >> 2;                       // 1152 (tail: 549)
        float4*       gv = (float4*)(out + (size_t)g0 * 18);
        const float4* lv = (const float4*)sv;
        for (int idx = t; idx < n4; idx += TPB) gv[idx] = lv[idx];
    }
    {
        int n4 = (ntet * 6) >> 2;                        // 384 (tail: 183)
        float4*       gt = (float4*)(out + V_ELEMS + (size_t)g0 * 6);
        const float4* lt = (const float4*)st;
        for (int idx = t; idx < n4; idx += TPB) gt[idx] = lt[idx];
    }
    {
        int n4 = (ntet * 2) >> 2;                        // 128 (tail: 61)
        float4*       gl = (float4*)(out + V_ELEMS + TRI_ELEMS + (size_t)g0 * 2);
        const float4* ll = (const float4*)sl;
        for (int idx = t; idx < n4; idx += TPB) gl[idx] = ll[idx];
    }
}

extern "C" void kernel_launch(void* const* d_in, const int* in_sizes, int n_in,
                              void* d_out, int out_size, void* d_ws, size_t ws_size,
                              hipStream_t stream) {
    const float* level = (const float*)d_in[0];
    float* out = (float*)d_out;
    int blocks = (NTET + TPB - 1) / TPB;
    mc_kernel<<<blocks, TPB, 0, stream>>>(level, out);
}